// Round 13
// baseline (27.304 us; speedup 1.0000x reference)
//
#include <hip/hip_runtime.h>
#include <hip/hip_bf16.h>

// Shapes: x,gn (8,128,64) f32; fb (1,128,32768) f32; resonance (64,128) f32.
// out (8,1,32768) f32.
// r[b,c,f] = sum_rr softmax(x+gn)[b,c,rr] * res[rr,f]
// out[b,s] = (1/128) * sum_c lerp(r[b,c,:], s) * fb[c,s]
//
// Model from R1-R12: dur ~= 9us fixed + sum(kernels). R13 minimizes issued
// instructions in both kernels (kA: no max-sub/no LDS/readlane broadcast,
// 64 float2 VMEM; kB: 32-band register cache -> 16 ds_read_b128 instead of
// 64, float4 fb loads, cq-shfl reduce). Structure = proven R6 two-kernel.

#define BATCH 8
#define BANDS 128
#define RES 64
#define NF 128
#define NS 32768
#define NBC (BATCH * BANDS)   // 1024
#define SEGK 64
#define NBLKB (NS / SEGK)     // 512
#define RSTRIDE 130           // padded b-row stride in LDS (bank spread)

// ---------------- Kernel A: softmax + matvec -> rT[f][b*128+c] ----------------
// One wave per bc row. No max-subtraction (logits <= ~16: exp safe in f32;
// identical ratio; validated R10/R11, absmax 1.2e-4). g broadcast via
// __shfl(g, rr) with unroll-constant rr -> v_readlane (SGPR operand, no LDS).
// Lane covers frames 2*lane, 2*lane+1 via one float2 res load per rr.
__global__ __launch_bounds__(64) void kA(const float* __restrict__ x,
                                         const float* __restrict__ gn,
                                         const float* __restrict__ res,
                                         float* __restrict__ rT) {
    const int bc = blockIdx.x;        // 0..1023
    const int t  = threadIdx.x;       // 0..63

    const float v = x[bc * RES + t] + gn[bc * RES + t];
    const float e = __expf(v);
    float ssum = e;
    #pragma unroll
    for (int off = 32; off > 0; off >>= 1)
        ssum += __shfl_xor(ssum, off);
    const float g = e / ssum;         // lane t holds g[t]

    const int f0 = t * 2;
    float r0 = 0.f, r1 = 0.f;
    #pragma unroll
    for (int rr = 0; rr < RES; ++rr) {
        const float gg = __shfl(g, rr);               // readlane: SGPR
        const float2 rv = *(const float2*)&res[rr * NF + f0];
        r0 = fmaf(gg, rv.x, r0);
        r1 = fmaf(gg, rv.y, r1);
    }
    rT[(f0 + 0) * NBC + bc] = r0;
    rT[(f0 + 1) * NBC + bc] = r1;
}

// ---------------- Kernel B: interp + fb dot + band mean ----------------
// Block k: samples [64k, 64k+63], all 8 batches. 256 thr, thread =
// (b = tid>>5, sq = (tid>>2)&7, cq = tid&3): owns band-quarter cq (32 bands,
// cached in 16 float4 regs via 16 ds_read_b128) x 8 samples (sq*8..+7).
// Partial sums reduced over the 4 cq lanes with 2 shfl_xor levels; cq==0
// stores 2 float4s. floor(pos) block-uniform for 64-aligned segments.
__global__ __launch_bounds__(256) void kB(const float* __restrict__ fb,
                                          const float* __restrict__ rT,
                                          float* __restrict__ out) {
    const int k   = blockIdx.x;        // 0..511
    const int tid = threadIdx.x;       // 0..255
    const int b   = tid >> 5;          // 0..7
    const int sq  = (tid >> 2) & 7;    // 0..7
    const int cq  = tid & 3;           // 0..3
    const int s0  = k * SEGK + sq * 8;

    __shared__ float rlo_s[BATCH * RSTRIDE];
    __shared__ float dd_s[BATCH * RSTRIDE];

    float pos0 = ((float)(k * SEGK) + 0.5f) * (1.0f / 256.0f) - 0.5f;
    pos0 = fminf(fmaxf(pos0, 0.0f), (float)(NF - 1));
    const int lo0 = (int)floorf(pos0);          // block-uniform
    const int f1  = min(lo0 + 1, NF - 1);

    for (int i = tid; i < NBC; i += 256) {
        const int bb = i >> 7, cc = i & 127;
        const float a  = rT[lo0 * NBC + i];
        const float h  = rT[f1  * NBC + i];
        rlo_s[bb * RSTRIDE + cc] = a;
        dd_s[bb * RSTRIDE + cc]  = h - a;
    }
    __syncthreads();

    // per-sample weights (8 samples)
    float w[8];
    #pragma unroll
    for (int i = 0; i < 8; ++i) {
        float p = ((float)(s0 + i) + 0.5f) * (1.0f / 256.0f) - 0.5f;
        p = fminf(fmaxf(p, 0.0f), (float)(NF - 1));
        w[i] = p - (float)lo0;
    }

    // cache this thread's 32-band quarter in registers
    const int cbase = cq * 32;
    const float* __restrict__ rl = &rlo_s[b * RSTRIDE + cbase];
    const float* __restrict__ dp = &dd_s[b * RSTRIDE + cbase];
    float4 rl4[8], dd4[8];
    #pragma unroll
    for (int ch = 0; ch < 8; ++ch) {
        rl4[ch] = *(const float4*)&rl[ch * 4];
        dd4[ch] = *(const float4*)&dp[ch * 4];
    }

    float acc[8];
    #pragma unroll
    for (int i = 0; i < 8; ++i) acc[i] = 0.f;

    #pragma unroll
    for (int ch = 0; ch < 8; ++ch) {
        const int band0 = cbase + ch * 4;
        #pragma unroll
        for (int j = 0; j < 4; ++j) {
            const float rv = (j == 0) ? rl4[ch].x : (j == 1) ? rl4[ch].y
                           : (j == 2) ? rl4[ch].z : rl4[ch].w;
            const float dv = (j == 0) ? dd4[ch].x : (j == 1) ? dd4[ch].y
                           : (j == 2) ? dd4[ch].z : dd4[ch].w;
            const float4 flo = *(const float4*)&fb[(band0 + j) * NS + s0];
            const float4 fhi = *(const float4*)&fb[(band0 + j) * NS + s0 + 4];
            acc[0] = fmaf(flo.x, fmaf(w[0], dv, rv), acc[0]);
            acc[1] = fmaf(flo.y, fmaf(w[1], dv, rv), acc[1]);
            acc[2] = fmaf(flo.z, fmaf(w[2], dv, rv), acc[2]);
            acc[3] = fmaf(flo.w, fmaf(w[3], dv, rv), acc[3]);
            acc[4] = fmaf(fhi.x, fmaf(w[4], dv, rv), acc[4]);
            acc[5] = fmaf(fhi.y, fmaf(w[5], dv, rv), acc[5]);
            acc[6] = fmaf(fhi.z, fmaf(w[6], dv, rv), acc[6]);
            acc[7] = fmaf(fhi.w, fmaf(w[7], dv, rv), acc[7]);
        }
    }

    // reduce across the 4 cq lanes (lane bits 0-1)
    #pragma unroll
    for (int i = 0; i < 8; ++i) {
        acc[i] += __shfl_xor(acc[i], 1);
        acc[i] += __shfl_xor(acc[i], 2);
    }

    if (cq == 0) {
        const float sc = 1.0f / (float)BANDS;
        float4 o0, o1;
        o0.x = acc[0] * sc; o0.y = acc[1] * sc; o0.z = acc[2] * sc; o0.w = acc[3] * sc;
        o1.x = acc[4] * sc; o1.y = acc[5] * sc; o1.z = acc[6] * sc; o1.w = acc[7] * sc;
        *(float4*)&out[b * NS + s0]     = o0;
        *(float4*)&out[b * NS + s0 + 4] = o1;
    }
}

extern "C" void kernel_launch(void* const* d_in, const int* in_sizes, int n_in,
                              void* d_out, int out_size, void* d_ws, size_t ws_size,
                              hipStream_t stream) {
    const float* x   = (const float*)d_in[0];
    const float* gn  = (const float*)d_in[1];
    const float* fb  = (const float*)d_in[2];
    const float* res = (const float*)d_in[3];
    float* out = (float*)d_out;
    float* rT  = (float*)d_ws;   // NF * NBC floats = 512 KB

    kA<<<NBC, 64, 0, stream>>>(x, gn, res, rT);
    kB<<<NBLKB, 256, 0, stream>>>(fb, rT, out);
}

// Round 14
// 16.223 us; speedup vs baseline: 1.6830x; 1.6830x over previous
//
#include <hip/hip_runtime.h>
#include <hip/hip_bf16.h>

// Shapes: x,gn (8,128,64) f32; fb (1,128,32768) f32; resonance (64,128) f32.
// out (8,1,32768) f32.
// r[b,c,f] = sum_rr softmax(x+gn)[b,c,rr] * res[rr,f]
// out[b,s] = (1/128) * sum_c lerp(r[b,c,:], s) * fb[c,s]
//
// Fused v4. ONE kernel, 256 blocks (4 batch-pairs x 64 segs of 512) x 512thr.
// Fixes for every prior fused failure:
//  - p1 redundancy = 128KB/block (own 2 batches only) = 33MB aggregate.
//  - p1 loads: 4 lanes/row, 16 contiguous elems/lane -> wave = contiguous
//    4KB (R5/R7/R9's strided-row reads were the killer).
//  - p1 reduce: quad shfl (2 levels x 5 vals) not 16-lane (R10: shfl storms
//    on the LDS pipe).
//  - p2: 2 samples/thread, r-pairs via wave-uniform-broadcast ds_read_b128
//    amortized over samples (R10 used 256 scalar ds_read_b32/thread).
//  - fb loads: sample index on low lane bits, float2 -> 512B/wave coalesced
//    (R13's fatal flaw: band index on low bits = 4MB-strided lanes).
//  - fb fan-out: bp-MAJOR block order (bi = bp*64+seg) -> the 4 blocks of a
//    seg share an XCD (bi%8 == seg%8), fb slice fetched once per L2.
// No atomics, no grid barrier, no d_ws, block-local syncs only.

#define BATCH 8
#define BANDS 128
#define RES 64
#define NF 128
#define NS 32768
#define SEG 512
#define NSEG (NS / SEG)    // 64
#define NBP 4              // batch pairs
#define NTHR 512

__global__ __launch_bounds__(NTHR, 2) void fused(const float* __restrict__ x,
                                                 const float* __restrict__ gn,
                                                 const float* __restrict__ fb,
                                                 const float* __restrict__ res,
                                                 float* __restrict__ out) {
    const int bi  = blockIdx.x;       // 0..255, bp-major
    const int bp  = bi >> 6;          // 0..3
    const int seg = bi & 63;          // 0..63
    const int tid = threadIdx.x;      // 0..511

    __shared__ float resc[4][RES];    // staged res columns [frame j][rr]
    __shared__ float r4[4][256];      // r per staged frame, row = bl*128+c

    const int fbase = 2 * seg - 1;    // lo in {2seg-1..2seg+1}; il=lo-fbase in 0..2

    if (tid < 4 * RES) {
        const int rr = tid >> 2, j = tid & 3;
        const int f = min(max(fbase + j, 0), NF - 1);
        resc[j][rr] = res[rr * NF + f];
    }
    __syncthreads();

    // ---- hoist this lane's resc slice (16 elems x 4 frames) to registers ----
    const int e0 = (tid & 3) * 16;    // elem-chunk start for this lane
    float4 cr[4][4];                  // [frame][j] over elems e0+4j..e0+4j+3
    #pragma unroll
    for (int f = 0; f < 4; ++f)
        #pragma unroll
        for (int j = 0; j < 4; ++j)
            cr[f][j] = *(const float4*)&resc[f][e0 + 4 * j];

    // ---- Phase 1: 256 rows (2 batches x 128 bands), 2 passes, 4 lanes/row ----
    const int q = tid >> 2;           // row-in-pass 0..127
    #pragma unroll
    for (int p = 0; p < 2; ++p) {
        const int row = p * 128 + q;  // 0..255
        const int bl  = row >> 7;
        const int c   = row & 127;
        const int bc  = (2 * bp + bl) * BANDS + c;

        const float4* __restrict__ xp = (const float4*)(x  + bc * RES + e0);
        const float4* __restrict__ gp = (const float4*)(gn + bc * RES + e0);

        float s = 0.f, d0 = 0.f, d1 = 0.f, d2 = 0.f, d3 = 0.f;
        #pragma unroll
        for (int j = 0; j < 4; ++j) {
            const float4 a = xp[j];
            const float4 b = gp[j];
            const float ex = __expf(a.x + b.x);
            const float ey = __expf(a.y + b.y);
            const float ez = __expf(a.z + b.z);
            const float ew = __expf(a.w + b.w);
            s += (ex + ey) + (ez + ew);
            d0 = fmaf(ex, cr[0][j].x, fmaf(ey, cr[0][j].y, fmaf(ez, cr[0][j].z, fmaf(ew, cr[0][j].w, d0))));
            d1 = fmaf(ex, cr[1][j].x, fmaf(ey, cr[1][j].y, fmaf(ez, cr[1][j].z, fmaf(ew, cr[1][j].w, d1))));
            d2 = fmaf(ex, cr[2][j].x, fmaf(ey, cr[2][j].y, fmaf(ez, cr[2][j].z, fmaf(ew, cr[2][j].w, d2))));
            d3 = fmaf(ex, cr[3][j].x, fmaf(ey, cr[3][j].y, fmaf(ez, cr[3][j].z, fmaf(ew, cr[3][j].w, d3))));
        }
        // reduce across the 4 lanes of the quad (lane bits 0-1)
        s  += __shfl_xor(s, 1);  s  += __shfl_xor(s, 2);
        d0 += __shfl_xor(d0, 1); d0 += __shfl_xor(d0, 2);
        d1 += __shfl_xor(d1, 1); d1 += __shfl_xor(d1, 2);
        d2 += __shfl_xor(d2, 1); d2 += __shfl_xor(d2, 2);
        d3 += __shfl_xor(d3, 1); d3 += __shfl_xor(d3, 2);

        if ((tid & 3) == 0) {
            const float inv = 1.0f / s;
            r4[0][row] = d0 * inv;
            r4[1][row] = d1 * inv;
            r4[2][row] = d2 * inv;
            r4[3][row] = d3 * inv;
        }
    }
    __syncthreads();

    // ---- Phase 2: thread = (bl = tid>>8, duo d = tid&255); samples s0,s0+1 ----
    const int bl = tid >> 8;
    const int d  = tid & 255;
    const int s0 = seg * SEG + 2 * d;

    float p0 = ((float)s0 + 0.5f) * (1.0f / 256.0f) - 0.5f;
    float p1 = ((float)s0 + 1.5f) * (1.0f / 256.0f) - 0.5f;
    p0 = fminf(fmaxf(p0, 0.0f), (float)(NF - 1));
    p1 = fminf(fmaxf(p1, 0.0f), (float)(NF - 1));
    const int lo = (int)floorf(p0);   // wave-uniform (128-sample wave spans
    const int il = lo - fbase;        //  never straddle s==127.5 mod 256)
    const float w0 = p0 - (float)lo;
    const float w1 = p1 - (float)lo;

    const float* __restrict__ rl = &r4[il][bl * BANDS];
    const float* __restrict__ rh = &r4[il + 1][bl * BANDS];

    float acc0 = 0.f, acc1 = 0.f;
    #pragma unroll 4
    for (int cc = 0; cc < BANDS / 4; ++cc) {
        const float4 rl4 = *(const float4*)&rl[4 * cc];   // broadcast b128
        const float4 rh4 = *(const float4*)&rh[4 * cc];   // broadcast b128
        const int band0 = 4 * cc;

        const float2 f0 = *(const float2*)&fb[(band0 + 0) * NS + s0];
        const float2 f1 = *(const float2*)&fb[(band0 + 1) * NS + s0];
        const float2 f2 = *(const float2*)&fb[(band0 + 2) * NS + s0];
        const float2 f3 = *(const float2*)&fb[(band0 + 3) * NS + s0];

        const float dx = rh4.x - rl4.x, dy = rh4.y - rl4.y;
        const float dz = rh4.z - rl4.z, dw = rh4.w - rl4.w;

        acc0 = fmaf(f0.x, fmaf(w0, dx, rl4.x), acc0);
        acc1 = fmaf(f0.y, fmaf(w1, dx, rl4.x), acc1);
        acc0 = fmaf(f1.x, fmaf(w0, dy, rl4.y), acc0);
        acc1 = fmaf(f1.y, fmaf(w1, dy, rl4.y), acc1);
        acc0 = fmaf(f2.x, fmaf(w0, dz, rl4.z), acc0);
        acc1 = fmaf(f2.y, fmaf(w1, dz, rl4.z), acc1);
        acc0 = fmaf(f3.x, fmaf(w0, dw, rl4.w), acc0);
        acc1 = fmaf(f3.y, fmaf(w1, dw, rl4.w), acc1);
    }

    float2 o;
    o.x = acc0 * (1.0f / (float)BANDS);
    o.y = acc1 * (1.0f / (float)BANDS);
    *(float2*)&out[(2 * bp + bl) * NS + s0] = o;
}

extern "C" void kernel_launch(void* const* d_in, const int* in_sizes, int n_in,
                              void* d_out, int out_size, void* d_ws, size_t ws_size,
                              hipStream_t stream) {
    const float* x   = (const float*)d_in[0];
    const float* gn  = (const float*)d_in[1];
    const float* fb  = (const float*)d_in[2];
    const float* res = (const float*)d_in[3];
    float* out = (float*)d_out;

    fused<<<NBP * NSEG, NTHR, 0, stream>>>(x, gn, fb, res, out);
}